// Round 6
// baseline (170.053 us; speedup 1.0000x reference)
//
#include <hip/hip_runtime.h>

#define B_DIM   4096
#define IN_DIM  4096
#define OUT_DIM 4096

typedef float floatx4 __attribute__((ext_vector_type(4)));
typedef __attribute__((address_space(1))) const void global_void;
typedef __attribute__((address_space(3))) void lds_void;

// K1: one WAVE per row, rows = 4096 weight rows + first 2048 input rows.
// Rows are staged through LDS via global_load_lds (fire-and-forget reads: no
// VGPR destinations, no compiler vmcnt batching) in two 8 KB halves per row,
// consumed in 4 KB chunks behind staged vmcnt waits.
//   ws[b]        = sum(input[b,:])          (b in [0,2048))
//   ws[4096 + o] = bias[o] * sum(weight[o,:])
__global__ __launch_bounds__(256) void k1_stage_sums(
    const float* __restrict__ input, const float* __restrict__ weight,
    const float* __restrict__ bias, float* __restrict__ ws)
{
    __shared__ float4 buf[2048];                  // 32 KB: wave w owns buf[w*512 ..)
    const int wave = threadIdx.x >> 6;
    const int lane = threadIdx.x & 63;
    const int rid  = blockIdx.x * 4 + wave;       // 0 .. 6143

    const bool is_w = rid < 4096;
    const float* src = is_w ? weight + (size_t)rid * IN_DIM
                            : input  + (size_t)(rid - 4096) * IN_DIM;
    const float4* g4 = (const float4*)src;        // 1024 float4 per row
    float4* lb = &buf[wave * 512];                // wave-uniform LDS base

    float s = 0.f;
    #pragma unroll
    for (int h = 0; h < 2; ++h) {                 // two 8 KB halves
        const float4* gh = g4 + h * 512;
        #pragma unroll
        for (int k = 0; k < 8; ++k)               // 8 KB in flight, zero VGPR dests
            __builtin_amdgcn_global_load_lds(
                (global_void*)(gh + k * 64 + lane),
                (lds_void*)(lb + k * 64), 16, 0, 0);

        asm volatile("s_waitcnt vmcnt(4)" ::: "memory");   // first 4 KB landed
        #pragma unroll
        for (int k = 0; k < 4; ++k) {
            float4 v = lb[k * 64 + lane];
            s += (v.x + v.y) + (v.z + v.w);
        }
        asm volatile("s_waitcnt vmcnt(0)" ::: "memory");   // second 4 KB landed
        #pragma unroll
        for (int k = 4; k < 8; ++k) {
            float4 v = lb[k * 64 + lane];
            s += (v.x + v.y) + (v.z + v.w);
        }
    }

    #pragma unroll
    for (int off = 32; off > 0; off >>= 1)
        s += __shfl_down(s, off, 64);

    if (lane == 0) {
        if (is_w) ws[4096 + rid] = s * bias[rid];
        else      ws[rid - 4096] = s;
    }
}

// K2: 2048 blocks. Block i: (a) write out row i (xs from ws, pure streaming
// write), (b) reduce input row r=2048+i with nt loads, (c) write out row r.
// bias/wb registers are reused across both rows; reads overlap the 64 MiB of
// nt writes across staggered blocks.
__global__ __launch_bounds__(256) void k2_fused(
    const float* __restrict__ input, const float* __restrict__ bias,
    const float* __restrict__ ws, float* __restrict__ out)
{
    const int i = blockIdx.x;                     // 0 .. 2047
    const int t = threadIdx.x;
    const int r = 2048 + i;

    // issue the input-row loads first (deepest latency)
    const floatx4* in4 = (const floatx4*)(input + (size_t)r * IN_DIM);
    floatx4 v[4];
    #pragma unroll
    for (int k = 0; k < 4; ++k)
        v[k] = __builtin_nontemporal_load(&in4[t + k * 256]);

    const floatx4* bias4 = (const floatx4*)bias;
    const floatx4* wb4   = (const floatx4*)(ws + 4096);
    floatx4 bi[4], wv[4];
    #pragma unroll
    for (int k = 0; k < 4; ++k) {
        bi[k] = bias4[t + k * 256];
        wv[k] = wb4[t + k * 256];
    }

    // row i: independent of the in-flight loads — fills the latency bubble
    const float xs_i = ws[i];
    floatx4* oi = (floatx4*)out + (size_t)i * (OUT_DIM / 4);
    #pragma unroll
    for (int k = 0; k < 4; ++k) {
        floatx4 rr;
        rr.x = fmaf(xs_i, bi[k].x, wv[k].x);
        rr.y = fmaf(xs_i, bi[k].y, wv[k].y);
        rr.z = fmaf(xs_i, bi[k].z, wv[k].z);
        rr.w = fmaf(xs_i, bi[k].w, wv[k].w);
        __builtin_nontemporal_store(rr, &oi[t + k * 256]);
    }

    // reduce row r
    float s = 0.f;
    #pragma unroll
    for (int k = 0; k < 4; ++k)
        s += (v[k].x + v[k].y) + (v[k].z + v[k].w);
    #pragma unroll
    for (int off = 32; off > 0; off >>= 1)
        s += __shfl_down(s, off, 64);

    __shared__ float sm[4];
    if ((t & 63) == 0) sm[t >> 6] = s;
    __syncthreads();
    const float xs_r = (sm[0] + sm[1]) + (sm[2] + sm[3]);

    floatx4* orow = (floatx4*)out + (size_t)r * (OUT_DIM / 4);
    #pragma unroll
    for (int k = 0; k < 4; ++k) {
        floatx4 rr;
        rr.x = fmaf(xs_r, bi[k].x, wv[k].x);
        rr.y = fmaf(xs_r, bi[k].y, wv[k].y);
        rr.z = fmaf(xs_r, bi[k].z, wv[k].z);
        rr.w = fmaf(xs_r, bi[k].w, wv[k].w);
        __builtin_nontemporal_store(rr, &orow[t + k * 256]);
    }
}

extern "C" void kernel_launch(void* const* d_in, const int* in_sizes, int n_in,
                              void* d_out, int out_size, void* d_ws, size_t ws_size,
                              hipStream_t stream) {
    const float* input  = (const float*)d_in[0];
    const float* weight = (const float*)d_in[1];
    const float* bias   = (const float*)d_in[2];
    float* out = (float*)d_out;
    float* ws  = (float*)d_ws;   // [0,2048): xs of first input rows; [4096,8192): bias*w_sum

    k1_stage_sums<<<(4096 + 2048) / 4, 256, 0, stream>>>(input, weight, bias, ws);
    k2_fused<<<2048, 256, 0, stream>>>(input, bias, ws, out);
}